// Round 1
// baseline (666.308 us; speedup 1.0000x reference)
//
#include <hip/hip_runtime.h>

typedef __bf16 bf16;
typedef bf16 bf16x8 __attribute__((ext_vector_type(8)));
typedef bf16 bf16x4 __attribute__((ext_vector_type(4)));
typedef float f32x4 __attribute__((ext_vector_type(4)));

#define AS1 __attribute__((address_space(1)))
#define AS3 __attribute__((address_space(3)))

__device__ __forceinline__ void load_lds16(const void* g, void* l) {
    __builtin_amdgcn_global_load_lds((const AS1 unsigned int*)g,
                                     (AS3 unsigned int*)l, 16, 0, 0);
}

// ---------------------------------------------------------------------------
// cast fp32 -> bf16 (vectorized)
// ---------------------------------------------------------------------------
__global__ __launch_bounds__(256) void cast_f32_bf16(
        const float* __restrict__ in, bf16* __restrict__ out, int n) {
    int i = (blockIdx.x * 256 + threadIdx.x) * 4;
    if (i < n) {
        float4 v = *(const float4*)(in + i);
        bf16x4 o = { (bf16)v.x, (bf16)v.y, (bf16)v.z, (bf16)v.w };
        *(bf16x4*)(out + i) = o;
    }
}

// ---------------------------------------------------------------------------
// transpose + cast: in fp32 [K][N] -> out bf16 [Np][K]; rows n in [N,Np) = 0
// ---------------------------------------------------------------------------
__global__ __launch_bounds__(256) void transpose_cast(
        const float* __restrict__ in, bf16* __restrict__ out,
        int K, int N, int Np) {
    __shared__ float tile[32][33];
    int bx = blockIdx.x * 32;  // n (output row)
    int by = blockIdx.y * 32;  // k
    int tx = threadIdx.x, ty = threadIdx.y;  // 32 x 8
#pragma unroll
    for (int i = 0; i < 4; ++i) {
        int k = by + ty + i * 8, n = bx + tx;
        float v = (k < K && n < N) ? in[(size_t)k * N + n] : 0.f;
        tile[ty + i * 8][tx] = v;
    }
    __syncthreads();
#pragma unroll
    for (int i = 0; i < 4; ++i) {
        int n = bx + ty + i * 8, k = by + tx;
        if (n < Np && k < K) out[(size_t)n * K + k] = (bf16)tile[tx][ty + i * 8];
    }
}

// ---------------------------------------------------------------------------
// GEMM: C[M][N] = A[M][K] * Bt[N][K]^T   (A row-major lda, Bt row-major ldb)
// 128x128 tile, BK=64, 4 waves (2x2), 16x16x32 bf16 MFMA. M,N%128==0, K%64==0
// ---------------------------------------------------------------------------
template <typename OutT>
__global__ __launch_bounds__(256) void gemm_bt(
        const bf16* __restrict__ A, const bf16* __restrict__ Bt,
        OutT* __restrict__ C, int K, int lda, int ldb, int ldc) {
    __shared__ __align__(16) bf16 As[128 * 64];
    __shared__ __align__(16) bf16 Bs[128 * 64];
    const int tid = threadIdx.x;
    const int wave = tid >> 6, lane = tid & 63;
    const int l15 = lane & 15, quad = lane >> 4;
    const int m0 = blockIdx.y * 128, n0 = blockIdx.x * 128;
    const int wm = (wave >> 1) * 64, wn = (wave & 1) * 64;

    f32x4 acc[4][4] = {};

    for (int k0 = 0; k0 < K; k0 += 64) {
#pragma unroll
        for (int c = 0; c < 4; ++c) {
            int e = wave * 2048 + c * 512 + lane * 8;  // element idx in tile
            int r = e >> 6, col = e & 63;
            load_lds16(A + (size_t)(m0 + r) * lda + k0 + col,
                       &As[wave * 2048 + c * 512]);
            load_lds16(Bt + (size_t)(n0 + r) * ldb + k0 + col,
                       &Bs[wave * 2048 + c * 512]);
        }
        __syncthreads();
#pragma unroll
        for (int kk = 0; kk < 64; kk += 32) {
            bf16x8 af[4], bf[4];
#pragma unroll
            for (int i = 0; i < 4; ++i)
                af[i] = *(const bf16x8*)&As[(wm + i * 16 + l15) * 64 + kk + quad * 8];
#pragma unroll
            for (int j = 0; j < 4; ++j)
                bf[j] = *(const bf16x8*)&Bs[(wn + j * 16 + l15) * 64 + kk + quad * 8];
#pragma unroll
            for (int i = 0; i < 4; ++i)
#pragma unroll
                for (int j = 0; j < 4; ++j)
                    acc[i][j] = __builtin_amdgcn_mfma_f32_16x16x32_bf16(
                        af[i], bf[j], acc[i][j], 0, 0, 0);
        }
        __syncthreads();
    }
#pragma unroll
    for (int i = 0; i < 4; ++i)
#pragma unroll
        for (int j = 0; j < 4; ++j) {
            int row = m0 + wm + i * 16 + quad * 4;
            int col = n0 + wn + j * 16 + l15;
#pragma unroll
            for (int r = 0; r < 4; ++r)
                C[(size_t)(row + r) * ldc + col] = (OutT)acc[i][j][r];
        }
}

// ---------------------------------------------------------------------------
// Flash attention (causal). Grid: (S/64, H, B), 256 threads (4 waves).
// Each wave owns 16 q-rows; block stages K-state (64x192) and V^T (128x64).
// qb: [B*S][3072] (h*192 + d), kvb: [B*S][4096] (h*256 + d),
// cb: [B*S][640] (k_rope at 512..575), ob: [B*S][2048] (h*128 + d)
// ---------------------------------------------------------------------------
__global__ __launch_bounds__(256) void mla_attention(
        const bf16* __restrict__ qb, const bf16* __restrict__ kvb,
        const bf16* __restrict__ cb, bf16* __restrict__ ob) {
    constexpr int S = 2048;
    const int qt = blockIdx.x, h = blockIdx.y, b = blockIdx.z;
    const int q0 = qt * 64;
    const int tid = threadIdx.x, wave = tid >> 6, lane = tid & 63;
    const int l15 = lane & 15, quad = lane >> 4;

    __shared__ __align__(16) bf16 Ks[64][200];   // 192 used, pad->200 (400B rows)
    __shared__ __align__(16) bf16 Vt[128][72];   // [vdim][kv], 64 used
    __shared__ __align__(16) bf16 Ps[4][16][72]; // per-wave P, 64 used

    // Q fragments (A-layout): row m = lane&15 of this wave's 16-row band
    bf16x8 qf[6];
    {
        const bf16* qrow = qb + (size_t)(b * S + q0 + wave * 16 + l15) * 3072 + h * 192;
#pragma unroll
        for (int ks = 0; ks < 6; ++ks)
            qf[ks] = *(const bf16x8*)(qrow + ks * 32 + quad * 8);
    }

    f32x4 o[8] = {};
    float m_i[4], l_i[4];
#pragma unroll
    for (int r = 0; r < 4; ++r) { m_i[r] = -1e30f; l_i[r] = 0.f; }

    const float sm_scale = 0.08838834764831845f * 1.4426950408889634f; // /sqrt(128)*log2e

    const int ntiles = qt + 1;
    for (int kt = 0; kt < ntiles; ++kt) {
        const int kv0 = kt * 64;
        // stage K-state: rows kv0..kv0+63, 192 dims (128 nope + 64 rope)
        {
            int r = tid >> 2, p = tid & 3;
            const bf16* krow_nope = kvb + (size_t)(b * S + kv0 + r) * 4096 + h * 256;
            const bf16* krow_rope = cb + (size_t)(b * S + kv0 + r) * 640 + 512;
#pragma unroll
            for (int cch = 0; cch < 6; ++cch) {
                int e = p * 48 + cch * 8;
                bf16x8 v = (e < 128) ? *(const bf16x8*)(krow_nope + e)
                                     : *(const bf16x8*)(krow_rope + (e - 128));
                *(bf16x8*)&Ks[r][e] = v;
            }
        }
        // stage V transposed: Vt[n][j] = V[kv0+j][n]
        {
            int j = tid >> 2, n0 = (tid & 3) * 32;
            const bf16* vrow = kvb + (size_t)(b * S + kv0 + j) * 4096 + h * 256 + 128;
#pragma unroll
            for (int cc = 0; cc < 4; ++cc) {
                bf16x8 v = *(const bf16x8*)(vrow + n0 + cc * 8);
#pragma unroll
                for (int u = 0; u < 8; ++u) Vt[n0 + cc * 8 + u][j] = v[u];
            }
        }
        __syncthreads();

        // scores: S16x64 = Q(16x192) * K^T
        f32x4 s[4];
#pragma unroll
        for (int nt = 0; nt < 4; ++nt) {
            f32x4 a = {};
#pragma unroll
            for (int ks = 0; ks < 6; ++ks) {
                bf16x8 kf = *(const bf16x8*)&Ks[nt * 16 + l15][ks * 32 + quad * 8];
                a = __builtin_amdgcn_mfma_f32_16x16x32_bf16(qf[ks], kf, a, 0, 0, 0);
            }
            s[nt] = a;
        }
        // mask + online softmax (C-layout: row=quad*4+r, col=nt*16+l15)
        float alpha[4];
        const int q_row = q0 + wave * 16 + quad * 4;
#pragma unroll
        for (int r = 0; r < 4; ++r) {
            float mx = -1e30f;
#pragma unroll
            for (int nt = 0; nt < 4; ++nt) {
                int k_idx = kv0 + nt * 16 + l15;
                float v = (k_idx <= q_row + r) ? s[nt][r] * sm_scale : -1e30f;
                s[nt][r] = v;
                mx = fmaxf(mx, v);
            }
#pragma unroll
            for (int off = 1; off < 16; off <<= 1)
                mx = fmaxf(mx, __shfl_xor(mx, off, 64));
            float m_new = fmaxf(m_i[r], mx);
            float su = 0.f;
#pragma unroll
            for (int nt = 0; nt < 4; ++nt) {
                float p = exp2f(s[nt][r] - m_new);
                s[nt][r] = p;
                su += p;
            }
#pragma unroll
            for (int off = 1; off < 16; off <<= 1)
                su += __shfl_xor(su, off, 64);
            alpha[r] = exp2f(m_i[r] - m_new);
            l_i[r] = l_i[r] * alpha[r] + su;
            m_i[r] = m_new;
        }
#pragma unroll
        for (int nt2 = 0; nt2 < 8; ++nt2)
#pragma unroll
            for (int r = 0; r < 4; ++r) o[nt2][r] *= alpha[r];
        // P: C-layout -> LDS -> A-layout
#pragma unroll
        for (int nt = 0; nt < 4; ++nt)
#pragma unroll
            for (int r = 0; r < 4; ++r)
                Ps[wave][quad * 4 + r][nt * 16 + l15] = (bf16)s[nt][r];
        __syncthreads();
        // O += P(16x64) * V(64x128)
#pragma unroll
        for (int kk = 0; kk < 64; kk += 32) {
            bf16x8 pf = *(const bf16x8*)&Ps[wave][l15][kk + quad * 8];
#pragma unroll
            for (int nt2 = 0; nt2 < 8; ++nt2) {
                bf16x8 vf = *(const bf16x8*)&Vt[nt2 * 16 + l15][kk + quad * 8];
                o[nt2] = __builtin_amdgcn_mfma_f32_16x16x32_bf16(pf, vf, o[nt2], 0, 0, 0);
            }
        }
        __syncthreads();
    }
    // epilogue: O / l
    bf16* orow = ob + (size_t)(b * S + q0 + wave * 16) * 2048 + h * 128;
#pragma unroll
    for (int nt2 = 0; nt2 < 8; ++nt2)
#pragma unroll
        for (int r = 0; r < 4; ++r) {
            float v = o[nt2][r] / l_i[r];
            orow[(size_t)(quad * 4 + r) * 2048 + nt2 * 16 + l15] = (bf16)v;
        }
}

// ---------------------------------------------------------------------------
// launch
// ---------------------------------------------------------------------------
extern "C" void kernel_launch(void* const* d_in, const int* in_sizes, int n_in,
                              void* d_out, int out_size, void* d_ws, size_t ws_size,
                              hipStream_t stream) {
    const float* x    = (const float*)d_in[0];
    const float* wqd  = (const float*)d_in[3];
    const float* wqu  = (const float*)d_in[4];
    const float* wkvd = (const float*)d_in[5];
    const float* wkvu = (const float*)d_in[6];
    const float* wout = (const float*)d_in[7];
    float* out = (float*)d_out;
    char* ws = (char*)d_ws;

    bf16* xb    = (bf16*)(ws + 0);          // 4096x2048
    bf16* wqdT  = (bf16*)(ws + 16777216);   // 768x2048
    bf16* wquT  = (bf16*)(ws + 19922944);   // 3072x768
    bf16* wkvdT = (bf16*)(ws + 24641536);   // 640x2048 (padded)
    bf16* wkvuT = (bf16*)(ws + 27262976);   // 4096x512
    bf16* woutT = (bf16*)(ws + 31457280);   // 2048x2048
    bf16* qd    = (bf16*)(ws + 39845888);   // 4096x768
    bf16* qb    = (bf16*)(ws + 46137344);   // 4096x3072
    bf16* cb    = (bf16*)(ws + 71303168);   // 4096x640
    bf16* kvb   = (bf16*)(ws + 76546048);   // 4096x4096
    bf16* attnb = (bf16*)(ws + 110100480);  // 4096x2048

    dim3 tb(32, 8);
    cast_f32_bf16<<<8192, 256, 0, stream>>>(x, xb, 8388608);
    transpose_cast<<<dim3(24, 64),  tb, 0, stream>>>(wqd,  wqdT,  2048, 768,  768);
    transpose_cast<<<dim3(96, 24),  tb, 0, stream>>>(wqu,  wquT,  768,  3072, 3072);
    transpose_cast<<<dim3(20, 64),  tb, 0, stream>>>(wkvd, wkvdT, 2048, 576,  640);
    transpose_cast<<<dim3(128, 16), tb, 0, stream>>>(wkvu, wkvuT, 512,  4096, 4096);
    transpose_cast<<<dim3(64, 64),  tb, 0, stream>>>(wout, woutT, 2048, 2048, 2048);

    gemm_bt<bf16><<<dim3(6, 32),  256, 0, stream>>>(xb, wqdT,  qd,  2048, 2048, 2048, 768);
    gemm_bt<bf16><<<dim3(24, 32), 256, 0, stream>>>(qd, wquT,  qb,  768,  768,  768,  3072);
    gemm_bt<bf16><<<dim3(5, 32),  256, 0, stream>>>(xb, wkvdT, cb,  2048, 2048, 2048, 640);
    gemm_bt<bf16><<<dim3(32, 32), 256, 0, stream>>>(cb, wkvuT, kvb, 512,  640,  512,  4096);

    mla_attention<<<dim3(32, 16, 2), 256, 0, stream>>>(qb, kvb, cb, attnb);

    gemm_bt<float><<<dim3(16, 32), 256, 0, stream>>>(attnb, woutT, out, 2048, 2048, 2048, 2048);
}

// Round 2
// 552.182 us; speedup vs baseline: 1.2067x; 1.2067x over previous
//
#include <hip/hip_runtime.h>

typedef __bf16 bf16;
typedef bf16 bf16x8 __attribute__((ext_vector_type(8)));
typedef bf16 bf16x4 __attribute__((ext_vector_type(4)));
typedef float f32x4 __attribute__((ext_vector_type(4)));
typedef short s16x4 __attribute__((ext_vector_type(4)));

#define AS1 __attribute__((address_space(1)))
#define AS3 __attribute__((address_space(3)))

__device__ __forceinline__ void load_lds16(const void* g, void* l) {
    __builtin_amdgcn_global_load_lds((const AS1 unsigned int*)g,
                                     (AS3 unsigned int*)l, 16, 0, 0);
}

// ---------------------------------------------------------------------------
// cast fp32 -> bf16 (vectorized)
// ---------------------------------------------------------------------------
__global__ __launch_bounds__(256) void cast_f32_bf16(
        const float* __restrict__ in, bf16* __restrict__ out, int n) {
    int i = (blockIdx.x * 256 + threadIdx.x) * 4;
    if (i < n) {
        float4 v = *(const float4*)(in + i);
        bf16x4 o = { (bf16)v.x, (bf16)v.y, (bf16)v.z, (bf16)v.w };
        *(bf16x4*)(out + i) = o;
    }
}

// ---------------------------------------------------------------------------
// transpose + cast: in fp32 [K][N] -> out bf16 [Np][K]; rows n in [N,Np) = 0
// ---------------------------------------------------------------------------
__global__ __launch_bounds__(256) void transpose_cast(
        const float* __restrict__ in, bf16* __restrict__ out,
        int K, int N, int Np) {
    __shared__ float tile[32][33];
    int bx = blockIdx.x * 32;  // n (output row)
    int by = blockIdx.y * 32;  // k
    int tx = threadIdx.x, ty = threadIdx.y;  // 32 x 8
#pragma unroll
    for (int i = 0; i < 4; ++i) {
        int k = by + ty + i * 8, n = bx + tx;
        float v = (k < K && n < N) ? in[(size_t)k * N + n] : 0.f;
        tile[ty + i * 8][tx] = v;
    }
    __syncthreads();
#pragma unroll
    for (int i = 0; i < 4; ++i) {
        int n = bx + ty + i * 8, k = by + tx;
        if (n < Np && k < K) out[(size_t)n * K + k] = (bf16)tile[tx][ty + i * 8];
    }
}

// ---------------------------------------------------------------------------
// GEMM: C[M][N] = A[M][K] * Bt[N][K]^T . 128x128 tile, BK=64, 4 waves.
// ---------------------------------------------------------------------------
template <typename OutT>
__global__ __launch_bounds__(256) void gemm_bt(
        const bf16* __restrict__ A, const bf16* __restrict__ Bt,
        OutT* __restrict__ C, int K, int lda, int ldb, int ldc) {
    __shared__ __align__(16) bf16 As[128 * 64];
    __shared__ __align__(16) bf16 Bs[128 * 64];
    const int tid = threadIdx.x;
    const int wave = tid >> 6, lane = tid & 63;
    const int l15 = lane & 15, quad = lane >> 4;
    const int m0 = blockIdx.y * 128, n0 = blockIdx.x * 128;
    const int wm = (wave >> 1) * 64, wn = (wave & 1) * 64;

    f32x4 acc[4][4] = {};

    for (int k0 = 0; k0 < K; k0 += 64) {
#pragma unroll
        for (int c = 0; c < 4; ++c) {
            int e = wave * 2048 + c * 512 + lane * 8;
            int r = e >> 6, col = e & 63;
            load_lds16(A + (size_t)(m0 + r) * lda + k0 + col,
                       &As[wave * 2048 + c * 512]);
            load_lds16(Bt + (size_t)(n0 + r) * ldb + k0 + col,
                       &Bs[wave * 2048 + c * 512]);
        }
        __syncthreads();
#pragma unroll
        for (int kk = 0; kk < 64; kk += 32) {
            bf16x8 af[4], bf[4];
#pragma unroll
            for (int i = 0; i < 4; ++i)
                af[i] = *(const bf16x8*)&As[(wm + i * 16 + l15) * 64 + kk + quad * 8];
#pragma unroll
            for (int j = 0; j < 4; ++j)
                bf[j] = *(const bf16x8*)&Bs[(wn + j * 16 + l15) * 64 + kk + quad * 8];
#pragma unroll
            for (int i = 0; i < 4; ++i)
#pragma unroll
                for (int j = 0; j < 4; ++j)
                    acc[i][j] = __builtin_amdgcn_mfma_f32_16x16x32_bf16(
                        af[i], bf[j], acc[i][j], 0, 0, 0);
        }
        __syncthreads();
    }
#pragma unroll
    for (int i = 0; i < 4; ++i)
#pragma unroll
        for (int j = 0; j < 4; ++j) {
            int row = m0 + wm + i * 16 + quad * 4;
            int col = n0 + wn + j * 16 + l15;
#pragma unroll
            for (int r = 0; r < 4; ++r)
                C[(size_t)(row + r) * ldc + col] = (OutT)acc[i][j][r];
        }
}

// ---------------------------------------------------------------------------
// Fused down-proj GEMM: Bt rows [0,768)=w_q_down^T -> C1, [768,1408)=w_kv_down^T -> C2
// ---------------------------------------------------------------------------
__global__ __launch_bounds__(256) void gemm_down(
        const bf16* __restrict__ A, const bf16* __restrict__ Bt,
        bf16* __restrict__ C1, bf16* __restrict__ C2) {
    const int K = 2048, lda = 2048, ldb = 2048;
    __shared__ __align__(16) bf16 As[128 * 64];
    __shared__ __align__(16) bf16 Bs[128 * 64];
    const int tid = threadIdx.x;
    const int wave = tid >> 6, lane = tid & 63;
    const int l15 = lane & 15, quad = lane >> 4;
    const int m0 = blockIdx.y * 128, n0 = blockIdx.x * 128;
    const int wm = (wave >> 1) * 64, wn = (wave & 1) * 64;

    f32x4 acc[4][4] = {};

    for (int k0 = 0; k0 < K; k0 += 64) {
#pragma unroll
        for (int c = 0; c < 4; ++c) {
            int e = wave * 2048 + c * 512 + lane * 8;
            int r = e >> 6, col = e & 63;
            load_lds16(A + (size_t)(m0 + r) * lda + k0 + col,
                       &As[wave * 2048 + c * 512]);
            load_lds16(Bt + (size_t)(n0 + r) * ldb + k0 + col,
                       &Bs[wave * 2048 + c * 512]);
        }
        __syncthreads();
#pragma unroll
        for (int kk = 0; kk < 64; kk += 32) {
            bf16x8 af[4], bf[4];
#pragma unroll
            for (int i = 0; i < 4; ++i)
                af[i] = *(const bf16x8*)&As[(wm + i * 16 + l15) * 64 + kk + quad * 8];
#pragma unroll
            for (int j = 0; j < 4; ++j)
                bf[j] = *(const bf16x8*)&Bs[(wn + j * 16 + l15) * 64 + kk + quad * 8];
#pragma unroll
            for (int i = 0; i < 4; ++i)
#pragma unroll
                for (int j = 0; j < 4; ++j)
                    acc[i][j] = __builtin_amdgcn_mfma_f32_16x16x32_bf16(
                        af[i], bf[j], acc[i][j], 0, 0, 0);
        }
        __syncthreads();
    }
    bf16* Cp; int ldc, coff;
    if (n0 < 768) { Cp = C1; ldc = 768; coff = 0; }
    else          { Cp = C2; ldc = 640; coff = 768; }
#pragma unroll
    for (int i = 0; i < 4; ++i)
#pragma unroll
        for (int j = 0; j < 4; ++j) {
            int row = m0 + wm + i * 16 + quad * 4;
            int col = n0 + wn + j * 16 + l15 - coff;
#pragma unroll
            for (int r = 0; r < 4; ++r)
                Cp[(size_t)(row + r) * ldc + col] = (bf16)acc[i][j][r];
        }
}

// ---------------------------------------------------------------------------
// Flash attention (causal), S^T formulation.
// Grid: (S/64, H, B), 256 threads (4 waves), qt reversed for load balance.
// Per kv-tile: stage K-state [64][192] and V^T [128][64] in LDS;
// S^T = K·Q^T (16x16x32 MFMA) -> softmax in-register -> O = P·V via
// 16x16x16 MFMA (P feeds A-operand directly from C-layout regs).
// ---------------------------------------------------------------------------
__global__ __launch_bounds__(256) void mla_attention(
        const bf16* __restrict__ qb, const bf16* __restrict__ kvb,
        const bf16* __restrict__ cb, bf16* __restrict__ ob) {
    constexpr int S = 2048;
    const int qt = gridDim.x - 1 - blockIdx.x;   // heavy blocks first
    const int h = blockIdx.y, b = blockIdx.z;
    const int q0 = qt * 64;
    const int tid = threadIdx.x, wave = tid >> 6, lane = tid & 63;
    const int l15 = lane & 15, quad = lane >> 4;

    __shared__ __align__(16) bf16 Ks[64][200];   // [kv][192], pad->200
    __shared__ __align__(16) bf16 Vt[128][72];   // [vdim][kv], 64 used

    // Q fragments (B-operand layout): lane&15 = qrow, k = quad*8+j
    const int qrow = q0 + wave * 16 + l15;
    bf16x8 qf[6];
    {
        const bf16* qr = qb + (size_t)(b * S + qrow) * 3072 + h * 192;
#pragma unroll
        for (int ks = 0; ks < 6; ++ks)
            qf[ks] = *(const bf16x8*)(qr + ks * 32 + quad * 8);
    }

    f32x4 o[8] = {};
    float m_i = -1e30f, l_i = 0.f;
    const float sm_scale = 0.08838834764831845f * 1.4426950408889634f;

    const int ntiles = qt + 1;
    // prefetch tile 0 into registers (lane = kv row; wave = column slice)
    bf16x8 kreg[6], vreg[4];
    {
        const bf16* kvr = kvb + (size_t)(b * S + 0 + lane) * 4096 + h * 256;
        const bf16* cbr = cb + (size_t)(b * S + 0 + lane) * 640 + 512;
#pragma unroll
        for (int c = 0; c < 6; ++c) {
            int col = wave * 48 + c * 8;
            kreg[c] = (col < 128) ? *(const bf16x8*)(kvr + col)
                                  : *(const bf16x8*)(cbr + col - 128);
        }
#pragma unroll
        for (int cc = 0; cc < 4; ++cc)
            vreg[cc] = *(const bf16x8*)(kvr + 128 + wave * 32 + cc * 8);
    }

    for (int kt = 0; kt < ntiles; ++kt) {
        __syncthreads();   // previous tile's compute done; LDS reusable
        // regs -> LDS (conflict-free: lane sweeps rows/banks)
#pragma unroll
        for (int c = 0; c < 6; ++c)
            *(bf16x8*)&Ks[lane][wave * 48 + c * 8] = kreg[c];
#pragma unroll
        for (int cc = 0; cc < 4; ++cc)
#pragma unroll
            for (int u = 0; u < 8; ++u)
                Vt[wave * 32 + cc * 8 + u][lane] = vreg[cc][u];
        __syncthreads();
        // prefetch next tile
        if (kt + 1 < ntiles) {
            const int kv0n = (kt + 1) * 64;
            const bf16* kvr = kvb + (size_t)(b * S + kv0n + lane) * 4096 + h * 256;
            const bf16* cbr = cb + (size_t)(b * S + kv0n + lane) * 640 + 512;
#pragma unroll
            for (int c = 0; c < 6; ++c) {
                int col = wave * 48 + c * 8;
                kreg[c] = (col < 128) ? *(const bf16x8*)(kvr + col)
                                      : *(const bf16x8*)(cbr + col - 128);
            }
#pragma unroll
            for (int cc = 0; cc < 4; ++cc)
                vreg[cc] = *(const bf16x8*)(kvr + 128 + wave * 32 + cc * 8);
        }

        // S^T = K * Q^T : D[m=kv][n=qrow]; C-layout row=quad*4+r=kv, col=l15=qrow
        const int kv0 = kt * 64;
        f32x4 s[4];
#pragma unroll
        for (int mt = 0; mt < 4; ++mt) {
            f32x4 a = {};
#pragma unroll
            for (int ks = 0; ks < 6; ++ks) {
                bf16x8 kf = *(const bf16x8*)&Ks[mt * 16 + l15][ks * 32 + quad * 8];
                a = __builtin_amdgcn_mfma_f32_16x16x32_bf16(kf, qf[ks], a, 0, 0, 0);
            }
            s[mt] = a;
        }

        // softmax: lane owns qrow=l15's 16 kv values (kv = kv0+mt*16+quad*4+r)
        float mx = -1e30f;
#pragma unroll
        for (int mt = 0; mt < 4; ++mt)
#pragma unroll
            for (int r = 0; r < 4; ++r) {
                int kvi = kv0 + mt * 16 + quad * 4 + r;
                float v = (kvi <= qrow) ? s[mt][r] * sm_scale : -1e30f;
                s[mt][r] = v;
                mx = fmaxf(mx, v);
            }
        mx = fmaxf(mx, __shfl_xor(mx, 16, 64));
        mx = fmaxf(mx, __shfl_xor(mx, 32, 64));
        float m_new = fmaxf(m_i, mx);
        float su = 0.f;
        bf16x4 pf[4];
#pragma unroll
        for (int mt = 0; mt < 4; ++mt)
#pragma unroll
            for (int r = 0; r < 4; ++r) {
                float p = exp2f(s[mt][r] - m_new);
                su += p;
                pf[mt][r] = (bf16)p;
            }
        su += __shfl_xor(su, 16, 64);
        su += __shfl_xor(su, 32, 64);
        float alpha = exp2f(m_i - m_new);
        l_i = l_i * alpha + su;
        m_i = m_new;
        // broadcast alpha to O's row layout (row = quad*4+r)
        float alpha_r[4];
#pragma unroll
        for (int r = 0; r < 4; ++r) alpha_r[r] = __shfl(alpha, quad * 4 + r, 64);
#pragma unroll
        for (int nt = 0; nt < 8; ++nt)
#pragma unroll
            for (int r = 0; r < 4; ++r) o[nt][r] *= alpha_r[r];

        // O += P * V : A-frag = pf (direct), B-frag = Vt b64 reads
#pragma unroll
        for (int ktk = 0; ktk < 4; ++ktk) {
            s16x4 a = __builtin_bit_cast(s16x4, pf[ktk]);
#pragma unroll
            for (int nt = 0; nt < 8; ++nt) {
                s16x4 bfv = __builtin_bit_cast(s16x4,
                    *(const bf16x4*)&Vt[nt * 16 + l15][ktk * 16 + quad * 4]);
                o[nt] = __builtin_amdgcn_mfma_f32_16x16x16bf16_1k(a, bfv, o[nt], 0, 0, 0);
            }
        }
    }

    // epilogue: O[qrow][vdim] / l ; row = quad*4+r, col = l15 (coalesced 32B)
    float l_r[4];
#pragma unroll
    for (int r = 0; r < 4; ++r) l_r[r] = __shfl(l_i, quad * 4 + r, 64);
    bf16* obase = ob + (size_t)(b * S + q0 + wave * 16) * 2048 + h * 128;
#pragma unroll
    for (int nt = 0; nt < 8; ++nt)
#pragma unroll
        for (int r = 0; r < 4; ++r)
            obase[(size_t)(quad * 4 + r) * 2048 + nt * 16 + l15] =
                (bf16)(o[nt][r] / l_r[r]);
}

// ---------------------------------------------------------------------------
// launch
// ---------------------------------------------------------------------------
extern "C" void kernel_launch(void* const* d_in, const int* in_sizes, int n_in,
                              void* d_out, int out_size, void* d_ws, size_t ws_size,
                              hipStream_t stream) {
    const float* x    = (const float*)d_in[0];
    const float* wqd  = (const float*)d_in[3];
    const float* wqu  = (const float*)d_in[4];
    const float* wkvd = (const float*)d_in[5];
    const float* wkvu = (const float*)d_in[6];
    const float* wout = (const float*)d_in[7];
    float* out = (float*)d_out;
    char* ws = (char*)d_ws;

    bf16* xb    = (bf16*)(ws + 0);          // 4096x2048
    bf16* wqdT  = (bf16*)(ws + 16777216);   // 768x2048   (adjacent to wkvdT!)
    bf16* wkvdT = (bf16*)(ws + 19922944);   // 640x2048
    bf16* wquT  = (bf16*)(ws + 22544384);   // 3072x768
    bf16* wkvuT = (bf16*)(ws + 27262976);   // 4096x512
    bf16* woutT = (bf16*)(ws + 31457280);   // 2048x2048
    bf16* qd    = (bf16*)(ws + 39845888);   // 4096x768
    bf16* qb    = (bf16*)(ws + 46137344);   // 4096x3072
    bf16* cb    = (bf16*)(ws + 71303168);   // 4096x640
    bf16* kvb   = (bf16*)(ws + 76546048);   // 4096x4096
    bf16* attnb = (bf16*)(ws + 110100480);  // 4096x2048

    dim3 tb(32, 8);
    cast_f32_bf16<<<8192, 256, 0, stream>>>(x, xb, 8388608);
    transpose_cast<<<dim3(24, 64),  tb, 0, stream>>>(wqd,  wqdT,  2048, 768,  768);
    transpose_cast<<<dim3(20, 64),  tb, 0, stream>>>(wkvd, wkvdT, 2048, 576,  640);
    transpose_cast<<<dim3(96, 24),  tb, 0, stream>>>(wqu,  wquT,  768,  3072, 3072);
    transpose_cast<<<dim3(128, 16), tb, 0, stream>>>(wkvu, wkvuT, 512,  4096, 4096);
    transpose_cast<<<dim3(64, 64),  tb, 0, stream>>>(wout, woutT, 2048, 2048, 2048);

    gemm_down<<<dim3(11, 32), 256, 0, stream>>>(xb, wqdT, qd, cb);
    gemm_bt<bf16><<<dim3(24, 32), 256, 0, stream>>>(qd, wquT,  qb,  768, 768, 768, 3072);
    gemm_bt<bf16><<<dim3(32, 32), 256, 0, stream>>>(cb, wkvuT, kvb, 512, 640, 512, 4096);

    mla_attention<<<dim3(32, 16, 2), 256, 0, stream>>>(qb, kvb, cb, attnb);

    gemm_bt<float><<<dim3(16, 32), 256, 0, stream>>>(attnb, woutT, out, 2048, 2048, 2048, 2048);
}

// Round 3
// 510.213 us; speedup vs baseline: 1.3059x; 1.0823x over previous
//
#include <hip/hip_runtime.h>

typedef __bf16 bf16;
typedef bf16 bf16x8 __attribute__((ext_vector_type(8)));
typedef bf16 bf16x4 __attribute__((ext_vector_type(4)));
typedef float f32x4 __attribute__((ext_vector_type(4)));
typedef short s16x4 __attribute__((ext_vector_type(4)));

#define AS1 __attribute__((address_space(1)))
#define AS3 __attribute__((address_space(3)))

__device__ __forceinline__ void load_lds16(const void* g, void* l) {
    __builtin_amdgcn_global_load_lds((const AS1 unsigned int*)g,
                                     (AS3 unsigned int*)l, 16, 0, 0);
}

// ---------------------------------------------------------------------------
// cast fp32 -> bf16 (vectorized)
// ---------------------------------------------------------------------------
__global__ __launch_bounds__(256) void cast_f32_bf16(
        const float* __restrict__ in, bf16* __restrict__ out, int n) {
    int i = (blockIdx.x * 256 + threadIdx.x) * 4;
    if (i < n) {
        float4 v = *(const float4*)(in + i);
        bf16x4 o = { (bf16)v.x, (bf16)v.y, (bf16)v.z, (bf16)v.w };
        *(bf16x4*)(out + i) = o;
    }
}

// ---------------------------------------------------------------------------
// transpose + cast: in fp32 [K][N] -> out bf16 [Np][K]; rows n in [N,Np) = 0
// ---------------------------------------------------------------------------
__global__ __launch_bounds__(256) void transpose_cast(
        const float* __restrict__ in, bf16* __restrict__ out,
        int K, int N, int Np) {
    __shared__ float tile[32][33];
    int bx = blockIdx.x * 32;  // n (output row)
    int by = blockIdx.y * 32;  // k
    int tx = threadIdx.x, ty = threadIdx.y;  // 32 x 8
#pragma unroll
    for (int i = 0; i < 4; ++i) {
        int k = by + ty + i * 8, n = bx + tx;
        float v = (k < K && n < N) ? in[(size_t)k * N + n] : 0.f;
        tile[ty + i * 8][tx] = v;
    }
    __syncthreads();
#pragma unroll
    for (int i = 0; i < 4; ++i) {
        int n = bx + ty + i * 8, k = by + tx;
        if (n < Np && k < K) out[(size_t)n * K + k] = (bf16)tile[tx][ty + i * 8];
    }
}

// ---------------------------------------------------------------------------
// GEMM: C[M][N] = A[M][K] * Bt[N][K]^T . 128x128 tile, BK=64, 4 waves.
// ---------------------------------------------------------------------------
template <typename OutT>
__global__ __launch_bounds__(256) void gemm_bt(
        const bf16* __restrict__ A, const bf16* __restrict__ Bt,
        OutT* __restrict__ C, int K, int lda, int ldb, int ldc) {
    __shared__ __align__(16) bf16 As[128 * 64];
    __shared__ __align__(16) bf16 Bs[128 * 64];
    const int tid = threadIdx.x;
    const int wave = tid >> 6, lane = tid & 63;
    const int l15 = lane & 15, quad = lane >> 4;
    const int m0 = blockIdx.y * 128, n0 = blockIdx.x * 128;
    const int wm = (wave >> 1) * 64, wn = (wave & 1) * 64;

    f32x4 acc[4][4] = {};

    for (int k0 = 0; k0 < K; k0 += 64) {
#pragma unroll
        for (int c = 0; c < 4; ++c) {
            int e = wave * 2048 + c * 512 + lane * 8;
            int r = e >> 6, col = e & 63;
            load_lds16(A + (size_t)(m0 + r) * lda + k0 + col,
                       &As[wave * 2048 + c * 512]);
            load_lds16(Bt + (size_t)(n0 + r) * ldb + k0 + col,
                       &Bs[wave * 2048 + c * 512]);
        }
        __syncthreads();
#pragma unroll
        for (int kk = 0; kk < 64; kk += 32) {
            bf16x8 af[4], bf[4];
#pragma unroll
            for (int i = 0; i < 4; ++i)
                af[i] = *(const bf16x8*)&As[(wm + i * 16 + l15) * 64 + kk + quad * 8];
#pragma unroll
            for (int j = 0; j < 4; ++j)
                bf[j] = *(const bf16x8*)&Bs[(wn + j * 16 + l15) * 64 + kk + quad * 8];
#pragma unroll
            for (int i = 0; i < 4; ++i)
#pragma unroll
                for (int j = 0; j < 4; ++j)
                    acc[i][j] = __builtin_amdgcn_mfma_f32_16x16x32_bf16(
                        af[i], bf[j], acc[i][j], 0, 0, 0);
        }
        __syncthreads();
    }
#pragma unroll
    for (int i = 0; i < 4; ++i)
#pragma unroll
        for (int j = 0; j < 4; ++j) {
            int row = m0 + wm + i * 16 + quad * 4;
            int col = n0 + wn + j * 16 + l15;
#pragma unroll
            for (int r = 0; r < 4; ++r)
                C[(size_t)(row + r) * ldc + col] = (OutT)acc[i][j][r];
        }
}

// ---------------------------------------------------------------------------
// Fused down-proj GEMM: Bt rows [0,768)=w_q_down^T -> C1, [768,1408)=w_kv_down^T -> C2
// ---------------------------------------------------------------------------
__global__ __launch_bounds__(256) void gemm_down(
        const bf16* __restrict__ A, const bf16* __restrict__ Bt,
        bf16* __restrict__ C1, bf16* __restrict__ C2) {
    const int K = 2048, lda = 2048, ldb = 2048;
    __shared__ __align__(16) bf16 As[128 * 64];
    __shared__ __align__(16) bf16 Bs[128 * 64];
    const int tid = threadIdx.x;
    const int wave = tid >> 6, lane = tid & 63;
    const int l15 = lane & 15, quad = lane >> 4;
    const int m0 = blockIdx.y * 128, n0 = blockIdx.x * 128;
    const int wm = (wave >> 1) * 64, wn = (wave & 1) * 64;

    f32x4 acc[4][4] = {};

    for (int k0 = 0; k0 < K; k0 += 64) {
#pragma unroll
        for (int c = 0; c < 4; ++c) {
            int e = wave * 2048 + c * 512 + lane * 8;
            int r = e >> 6, col = e & 63;
            load_lds16(A + (size_t)(m0 + r) * lda + k0 + col,
                       &As[wave * 2048 + c * 512]);
            load_lds16(Bt + (size_t)(n0 + r) * ldb + k0 + col,
                       &Bs[wave * 2048 + c * 512]);
        }
        __syncthreads();
#pragma unroll
        for (int kk = 0; kk < 64; kk += 32) {
            bf16x8 af[4], bf[4];
#pragma unroll
            for (int i = 0; i < 4; ++i)
                af[i] = *(const bf16x8*)&As[(wm + i * 16 + l15) * 64 + kk + quad * 8];
#pragma unroll
            for (int j = 0; j < 4; ++j)
                bf[j] = *(const bf16x8*)&Bs[(wn + j * 16 + l15) * 64 + kk + quad * 8];
#pragma unroll
            for (int i = 0; i < 4; ++i)
#pragma unroll
                for (int j = 0; j < 4; ++j)
                    acc[i][j] = __builtin_amdgcn_mfma_f32_16x16x32_bf16(
                        af[i], bf[j], acc[i][j], 0, 0, 0);
        }
        __syncthreads();
    }
    bf16* Cp; int ldc, coff;
    if (n0 < 768) { Cp = C1; ldc = 768; coff = 0; }
    else          { Cp = C2; ldc = 640; coff = 768; }
#pragma unroll
    for (int i = 0; i < 4; ++i)
#pragma unroll
        for (int j = 0; j < 4; ++j) {
            int row = m0 + wm + i * 16 + quad * 4;
            int col = n0 + wn + j * 16 + l15 - coff;
#pragma unroll
            for (int r = 0; r < 4; ++r)
                Cp[(size_t)(row + r) * ldc + col] = (bf16)acc[i][j][r];
        }
}

// ---------------------------------------------------------------------------
// Flash attention (causal), S^T formulation, 8 waves / 128 q-rows per block.
// Grid: (S/128, H, B); qt reversed (heavy first). Per 64-kv tile:
//  - K-state tile (64x192) staged DMA-style via global_load_lds into
//    FRAGMENT-MAJOR layout: block (mt,ks) of 16 kv x 32 feat; granule g
//    (16B) holds rows g&15, col-chunk g>>4 -> MFMA read = base+lane*16,
//    conflict-free, zero VALU staging.
//  - V^T (128x64) via register prefetch + scalar LDS writes (stride 68).
//  - S^T = K*Q^T (16x16x32), softmax in-register (lane owns qrow=l15),
//    O += P*V via 16x16x16 (P is already A-layout in regs).
// ---------------------------------------------------------------------------
__global__ __launch_bounds__(512) void mla_attention(
        const bf16* __restrict__ qb, const bf16* __restrict__ kvb,
        const bf16* __restrict__ cb, bf16* __restrict__ ob) {
    constexpr int S = 2048;
    const int qt = gridDim.x - 1 - blockIdx.x;   // heavy blocks first
    const int h = blockIdx.y, b = blockIdx.z;
    const int q0 = qt * 128;
    const int tid = threadIdx.x, wave = tid >> 6, lane = tid & 63;
    const int l15 = lane & 15, quad = lane >> 4;

    __shared__ __align__(16) bf16 Ks[24 * 512];    // fragment-major, 24 KB
    __shared__ __align__(16) bf16 Vt[128 * 68];    // [vdim][kv], 17 KB

    const int qrow = q0 + wave * 16 + l15;
    bf16x8 qf[6];
    {
        const bf16* qr = qb + (size_t)(b * S + qrow) * 3072 + h * 192;
#pragma unroll
        for (int ks = 0; ks < 6; ++ks)
            qf[ks] = *(const bf16x8*)(qr + ks * 32 + quad * 8);
    }

    f32x4 o[8] = {};
    float m_i = -1e30f, l_i = 0.f;
    const float sm_scale = 0.08838834764831845f * 1.4426950408889634f;

    const int ntiles = 2 * qt + 2;
    const int qmax_w = q0 + wave * 16 + 15;   // last row this wave owns

    // K staging assignment: wave handles frag-blocks bi = wave*3 + {0,1,2}
    // bi -> (mt = bi/6, ks = bi%6); lane loads row mt*16+(lane&15),
    // col-chunk (lane>>4)*8 within the 32-col slab.
    // V prefetch: thread holds V[kv=lane][vdim = wave*16 + c*8 + u].
    bf16x8 vreg[2];
    {
        const bf16* vr = kvb + (size_t)(b * S + lane) * 4096 + h * 256 + 128 + wave * 16;
        vreg[0] = *(const bf16x8*)(vr);
        vreg[1] = *(const bf16x8*)(vr + 8);
    }

    for (int kt = 0; kt < ntiles; ++kt) {
        const int kv0 = kt * 64;
        __syncthreads();   // prev tile's compute done; LDS reusable
        // issue async K DMA (3 blocks per wave)
#pragma unroll
        for (int i = 0; i < 3; ++i) {
            const int bi = wave * 3 + i;
            const int mt = bi / 6, ks = bi % 6;
            const size_t row = (size_t)(b * S + kv0 + mt * 16 + l15);
            const bf16* g = (ks < 4)
                ? kvb + row * 4096 + h * 256 + ks * 32 + quad * 8
                : cb  + row * 640  + 512 + (ks - 4) * 32 + quad * 8;
            load_lds16(g, &Ks[bi * 512]);
        }
        // V regs -> LDS (write conflict-free: lane sweeps banks)
#pragma unroll
        for (int c = 0; c < 2; ++c)
#pragma unroll
            for (int u = 0; u < 8; ++u)
                Vt[(wave * 16 + c * 8 + u) * 68 + lane] = vreg[c][u];
        __syncthreads();   // drains DMA (vmcnt) + LDS writes

        // prefetch next tile's V
        if (kt + 1 < ntiles) {
            const bf16* vr = kvb + (size_t)(b * S + (kt + 1) * 64 + lane) * 4096
                             + h * 256 + 128 + wave * 16;
            vreg[0] = *(const bf16x8*)(vr);
            vreg[1] = *(const bf16x8*)(vr + 8);
        }

        if (kv0 > qmax_w) continue;   // fully-masked band: skip compute

        // S^T = K * Q^T ; C-layout: row(quad*4+r)=kv, col(l15)=qrow
        f32x4 s[4];
#pragma unroll
        for (int mt = 0; mt < 4; ++mt) {
            f32x4 a = {};
#pragma unroll
            for (int ks = 0; ks < 6; ++ks) {
                bf16x8 kf = *(const bf16x8*)&Ks[(mt * 6 + ks) * 512 + lane * 8];
                a = __builtin_amdgcn_mfma_f32_16x16x32_bf16(kf, qf[ks], a, 0, 0, 0);
            }
            s[mt] = a;
        }

        // online softmax: lane owns qrow=l15's 16 kv values
        float mx = -1e30f;
#pragma unroll
        for (int mt = 0; mt < 4; ++mt)
#pragma unroll
            for (int r = 0; r < 4; ++r) {
                int kvi = kv0 + mt * 16 + quad * 4 + r;
                float v = (kvi <= qrow) ? s[mt][r] * sm_scale : -1e30f;
                s[mt][r] = v;
                mx = fmaxf(mx, v);
            }
        mx = fmaxf(mx, __shfl_xor(mx, 16, 64));
        mx = fmaxf(mx, __shfl_xor(mx, 32, 64));
        float m_new = fmaxf(m_i, mx);
        float su = 0.f;
        bf16x4 pf[4];
#pragma unroll
        for (int mt = 0; mt < 4; ++mt)
#pragma unroll
            for (int r = 0; r < 4; ++r) {
                float p = exp2f(s[mt][r] - m_new);
                su += p;
                pf[mt][r] = (bf16)p;
            }
        su += __shfl_xor(su, 16, 64);
        su += __shfl_xor(su, 32, 64);
        float alpha = exp2f(m_i - m_new);
        l_i = l_i * alpha + su;
        m_i = m_new;
        float alpha_r[4];
#pragma unroll
        for (int r = 0; r < 4; ++r) alpha_r[r] = __shfl(alpha, quad * 4 + r, 64);
#pragma unroll
        for (int nt = 0; nt < 8; ++nt)
#pragma unroll
            for (int r = 0; r < 4; ++r) o[nt][r] *= alpha_r[r];

        // O += P * V
#pragma unroll
        for (int ktk = 0; ktk < 4; ++ktk) {
            s16x4 a = __builtin_bit_cast(s16x4, pf[ktk]);
#pragma unroll
            for (int nt = 0; nt < 8; ++nt) {
                s16x4 bfv = __builtin_bit_cast(s16x4,
                    *(const bf16x4*)&Vt[(nt * 16 + l15) * 68 + ktk * 16 + quad * 4]);
                o[nt] = __builtin_amdgcn_mfma_f32_16x16x16bf16_1k(a, bfv, o[nt], 0, 0, 0);
            }
        }
    }

    // epilogue
    float l_r[4];
#pragma unroll
    for (int r = 0; r < 4; ++r) l_r[r] = __shfl(l_i, quad * 4 + r, 64);
    bf16* obase = ob + (size_t)(b * S + q0 + wave * 16) * 2048 + h * 128;
#pragma unroll
    for (int nt = 0; nt < 8; ++nt)
#pragma unroll
        for (int r = 0; r < 4; ++r)
            obase[(size_t)(quad * 4 + r) * 2048 + nt * 16 + l15] =
                (bf16)(o[nt][r] / l_r[r]);
}

// ---------------------------------------------------------------------------
// launch
// ---------------------------------------------------------------------------
extern "C" void kernel_launch(void* const* d_in, const int* in_sizes, int n_in,
                              void* d_out, int out_size, void* d_ws, size_t ws_size,
                              hipStream_t stream) {
    const float* x    = (const float*)d_in[0];
    const float* wqd  = (const float*)d_in[3];
    const float* wqu  = (const float*)d_in[4];
    const float* wkvd = (const float*)d_in[5];
    const float* wkvu = (const float*)d_in[6];
    const float* wout = (const float*)d_in[7];
    float* out = (float*)d_out;
    char* ws = (char*)d_ws;

    bf16* xb    = (bf16*)(ws + 0);          // 4096x2048
    bf16* wqdT  = (bf16*)(ws + 16777216);   // 768x2048   (adjacent to wkvdT!)
    bf16* wkvdT = (bf16*)(ws + 19922944);   // 640x2048
    bf16* wquT  = (bf16*)(ws + 22544384);   // 3072x768
    bf16* wkvuT = (bf16*)(ws + 27262976);   // 4096x512
    bf16* woutT = (bf16*)(ws + 31457280);   // 2048x2048
    bf16* qd    = (bf16*)(ws + 39845888);   // 4096x768
    bf16* qb    = (bf16*)(ws + 46137344);   // 4096x3072
    bf16* cb    = (bf16*)(ws + 71303168);   // 4096x640
    bf16* kvb   = (bf16*)(ws + 76546048);   // 4096x4096
    bf16* attnb = (bf16*)(ws + 110100480);  // 4096x2048

    dim3 tb(32, 8);
    cast_f32_bf16<<<8192, 256, 0, stream>>>(x, xb, 8388608);
    transpose_cast<<<dim3(24, 64),  tb, 0, stream>>>(wqd,  wqdT,  2048, 768,  768);
    transpose_cast<<<dim3(20, 64),  tb, 0, stream>>>(wkvd, wkvdT, 2048, 576,  640);
    transpose_cast<<<dim3(96, 24),  tb, 0, stream>>>(wqu,  wquT,  768,  3072, 3072);
    transpose_cast<<<dim3(128, 16), tb, 0, stream>>>(wkvu, wkvuT, 512,  4096, 4096);
    transpose_cast<<<dim3(64, 64),  tb, 0, stream>>>(wout, woutT, 2048, 2048, 2048);

    gemm_down<<<dim3(11, 32), 256, 0, stream>>>(xb, wqdT, qd, cb);
    gemm_bt<bf16><<<dim3(24, 32), 256, 0, stream>>>(qd, wquT,  qb,  768, 768, 768, 3072);
    gemm_bt<bf16><<<dim3(32, 32), 256, 0, stream>>>(cb, wkvuT, kvb, 512, 640, 512, 4096);

    mla_attention<<<dim3(16, 16, 2), 512, 0, stream>>>(qb, kvb, cb, attnb);

    gemm_bt<float><<<dim3(16, 32), 256, 0, stream>>>(attnb, woutT, out, 2048, 2048, 2048, 2048);
}